// Round 6
// baseline (150.658 us; speedup 1.0000x reference)
//
#include <hip/hip_runtime.h>
#include <math.h>

#define BB 8
#define NCC 1024
#define NTT 1024
#define HH 128
#define DYY 32
#define NTB 16                   // 512 blocks x 512 threads -> 2 blocks/CU
#define LOG2E 1.44269504088896340736f

// DS-pipe theory (r5): R0/R1/R4 all plateau ~42-47us at VALUBusy ~33% with
// 12-16k DS wave-instrs per CU ~= 25-40us of per-CU LDS-pipe serialization.
// This round removes phase-2 LDS entirely: y/xc read global->reg with
// distance-2 prefetch (r2 failed for lack of prefetch, not direct-L2 per se).
// (r5 attempt hit an infra failure -- container died twice, no counters --
// source re-audited for bounds/races/hangs and resubmitted unchanged.)
//
// LDS arena: 18480 floats = 73.9 KB (x2 blocks = 147.8 <= 160 KB/CU).
//   phase 1 (aliases CMB): HB[0,2112) RED[2112,2496) WCH[2496,6592)
//   epilogue: CMB [0,18432): 512 rows (16 t x 32 (nh,ns)) x 36 (32 d + l + pad)
//   SIGL [18432,18480): outside CMB -> no fence needed between late sigl
//        readers and early dump writers
#define HB 0
#define RED 2112
#define WCH 2496
#define SIGL 18432
#define SMEM_SZ 18480
#define CMB 0
#define HSTRIDE 132              // mult of 4 (aligned b128); p vs p+8 = 2-way = free

// Phase 2 mapping: wave=(tq 0..3, nh 0..1) owns 4 targets x 512 contexts;
// lane=(ns 0..15, dg, th): th picks 2 of the wave's 4 targets, lane owns ONE
// context per 16-n tile, reads y[n][dg*16..+16] (4 consecutive float4) and
// xc[n] straight from global (L2) with distance-2 register prefetch. No LDS
// in the loop. y re-read 4x across tq-waves (~256MB L2): XCD swizzle pins
// each batch's 1MB yc slice to one XCD's private 4MB L2 (512 = 8 XCDs x 64).
// P<=0 (sig>0) => exp(P)<=1: no max subtraction.

#define PLOAD(T, Y0, Y1, Y2, Y3, X0, X1, X2)                                   \
    do {                                                                       \
        const int n_ = nst + (T) * 16 + ns2;                                   \
        const float4* pv_ = ycB4 + n_ * 8 + dg * 4;                            \
        Y0 = pv_[0]; Y1 = pv_[1]; Y2 = pv_[2]; Y3 = pv_[3];                    \
        const float* px_ = xcB + n_ * 3;                                       \
        X0 = px_[0]; X1 = px_[1]; X2 = px_[2];                                 \
    } while (0)

#define PTILE(X0, X1, X2, Y0, Y1, Y2, Y3)                                      \
    do {                                                                       \
        float d0_ = (X0) - a00, d1_ = (X1) - a01, d2_ = (X2) - a02;            \
        float pp_ = fmaf(s00, d0_ * d0_, fmaf(s01, d1_ * d1_, s02 * (d2_ * d2_))); \
        const float e0_ = exp2f(-pp_);                                         \
        l0 += e0_;                                                             \
        d0_ = (X0) - a10; d1_ = (X1) - a11; d2_ = (X2) - a12;                  \
        pp_ = fmaf(s10, d0_ * d0_, fmaf(s11, d1_ * d1_, s12 * (d2_ * d2_)));   \
        const float e1_ = exp2f(-pp_);                                         \
        l1 += e1_;                                                             \
        acc0[0]  = fmaf(e0_, (Y0).x, acc0[0]);                                 \
        acc0[1]  = fmaf(e0_, (Y0).y, acc0[1]);                                 \
        acc0[2]  = fmaf(e0_, (Y0).z, acc0[2]);                                 \
        acc0[3]  = fmaf(e0_, (Y0).w, acc0[3]);                                 \
        acc0[4]  = fmaf(e0_, (Y1).x, acc0[4]);                                 \
        acc0[5]  = fmaf(e0_, (Y1).y, acc0[5]);                                 \
        acc0[6]  = fmaf(e0_, (Y1).z, acc0[6]);                                 \
        acc0[7]  = fmaf(e0_, (Y1).w, acc0[7]);                                 \
        acc0[8]  = fmaf(e0_, (Y2).x, acc0[8]);                                 \
        acc0[9]  = fmaf(e0_, (Y2).y, acc0[9]);                                 \
        acc0[10] = fmaf(e0_, (Y2).z, acc0[10]);                                \
        acc0[11] = fmaf(e0_, (Y2).w, acc0[11]);                                \
        acc0[12] = fmaf(e0_, (Y3).x, acc0[12]);                                \
        acc0[13] = fmaf(e0_, (Y3).y, acc0[13]);                                \
        acc0[14] = fmaf(e0_, (Y3).z, acc0[14]);                                \
        acc0[15] = fmaf(e0_, (Y3).w, acc0[15]);                                \
        acc1[0]  = fmaf(e1_, (Y0).x, acc1[0]);                                 \
        acc1[1]  = fmaf(e1_, (Y0).y, acc1[1]);                                 \
        acc1[2]  = fmaf(e1_, (Y0).z, acc1[2]);                                 \
        acc1[3]  = fmaf(e1_, (Y0).w, acc1[3]);                                 \
        acc1[4]  = fmaf(e1_, (Y1).x, acc1[4]);                                 \
        acc1[5]  = fmaf(e1_, (Y1).y, acc1[5]);                                 \
        acc1[6]  = fmaf(e1_, (Y1).z, acc1[6]);                                 \
        acc1[7]  = fmaf(e1_, (Y1).w, acc1[7]);                                 \
        acc1[8]  = fmaf(e1_, (Y2).x, acc1[8]);                                 \
        acc1[9]  = fmaf(e1_, (Y2).y, acc1[9]);                                 \
        acc1[10] = fmaf(e1_, (Y2).z, acc1[10]);                                \
        acc1[11] = fmaf(e1_, (Y2).w, acc1[11]);                                \
        acc1[12] = fmaf(e1_, (Y3).x, acc1[12]);                                \
        acc1[13] = fmaf(e1_, (Y3).y, acc1[13]);                                \
        acc1[14] = fmaf(e1_, (Y3).z, acc1[14]);                                \
        acc1[15] = fmaf(e1_, (Y3).w, acc1[15]);                                \
    } while (0)

__global__ __launch_bounds__(512, 2) void k_fused(const float* __restrict__ xc,
                                                  const float* __restrict__ yc,
                                                  const float* __restrict__ xt,
                                                  const float* __restrict__ W0,
                                                  const float* __restrict__ b0,
                                                  const float* __restrict__ W1,
                                                  const float* __restrict__ b1,
                                                  const float* __restrict__ W2,
                                                  const float* __restrict__ b2,
                                                  const float* __restrict__ W3,
                                                  const float* __restrict__ b3,
                                                  float* __restrict__ out) {
    const int tid = threadIdx.x;
    const int phys = blockIdx.x;
    const int bid = (phys & 7) * 64 + (phys >> 3);   // XCD swizzle: batch<->XCD
    const int t0 = bid * NTB;            // global target base (xt/out flat B*Nt)
    const int b = bid >> 6;              // 64 blocks per batch
    const int wv = tid >> 6;             // wave 0..7
    const int lane = tid & 63;

    __shared__ float smem[SMEM_SZ];

    // ================= phase 1: MLP (unchanged from r4) =================
    const int jg = tid >> 4;             // 0..31 col-group (4 cols)
    const int p = tid & 15;              // 0..15 point
    const int j0 = jg * 4;
    const int jl4 = (jg & 3) * 4;        // col offset within the wave's W slice
    float* hrow = smem + HB + p * HSTRIDE;

    {
        const float* xr = xt + (size_t)(t0 + p) * 3;
        const float x0 = xr[0], x1 = xr[1], x2 = xr[2];
        const float4* W0v = (const float4*)W0;
        const float4 w0a = W0v[jg], w0b = W0v[32 + jg], w0c = W0v[64 + jg];
        const float4 bb0 = ((const float4*)b0)[jg];
        float4 h0;
        h0.x = fmaxf(fmaf(x0, w0a.x, fmaf(x1, w0b.x, fmaf(x2, w0c.x, bb0.x))), 0.f);
        h0.y = fmaxf(fmaf(x0, w0a.y, fmaf(x1, w0b.y, fmaf(x2, w0c.y, bb0.y))), 0.f);
        h0.z = fmaxf(fmaf(x0, w0a.z, fmaf(x1, w0b.z, fmaf(x2, w0c.z, bb0.z))), 0.f);
        h0.w = fmaxf(fmaf(x0, w0a.w, fmaf(x1, w0b.w, fmaf(x2, w0c.w, bb0.w))), 0.f);
        *(float4*)(hrow + j0) = h0;
    }

    const int gWb = (lane >> 2) * 32 + wv * 4 + (lane & 3);
    float* wwb = smem + WCH + wv * 512;
    const float4* __restrict__ W1v = (const float4*)W1;
    const float4* __restrict__ W2v = (const float4*)W2;

    float4 wA0 = W1v[gWb], wA1 = W1v[gWb + 512];
    __syncthreads();                     // h(L0) visible

    auto run_layer = [&](const float4* __restrict__ Wv, const float4 bi,
                         float4 r0, float4 r1) -> float4 {
        float a0 = bi.x, a1 = bi.y, a2 = bi.z, a3 = bi.w;
        ((float4*)wwb)[lane] = r0;
        float4 wcur = r1;
#pragma unroll
        for (int c = 0; c < 8; ++c) {
            float4 wnext;
            if (c < 6) wnext = Wv[gWb + (c + 2) * 512];
            if (c < 7) ((float4*)(wwb + ((c + 1) & 1) * 256))[lane] = wcur;
            const float* wbc = wwb + (c & 1) * 256;
#pragma unroll
            for (int q = 0; q < 4; ++q) {
                const float4 ch = *(const float4*)(hrow + c * 16 + q * 4);
                const float4 k0 = *(const float4*)(wbc + (q * 4 + 0) * 16 + jl4);
                const float4 k1 = *(const float4*)(wbc + (q * 4 + 1) * 16 + jl4);
                const float4 k2 = *(const float4*)(wbc + (q * 4 + 2) * 16 + jl4);
                const float4 k3 = *(const float4*)(wbc + (q * 4 + 3) * 16 + jl4);
                a0 = fmaf(ch.x, k0.x, a0);
                a1 = fmaf(ch.x, k0.y, a1);
                a2 = fmaf(ch.x, k0.z, a2);
                a3 = fmaf(ch.x, k0.w, a3);
                a0 = fmaf(ch.y, k1.x, a0);
                a1 = fmaf(ch.y, k1.y, a1);
                a2 = fmaf(ch.y, k1.z, a2);
                a3 = fmaf(ch.y, k1.w, a3);
                a0 = fmaf(ch.z, k2.x, a0);
                a1 = fmaf(ch.z, k2.y, a1);
                a2 = fmaf(ch.z, k2.z, a2);
                a3 = fmaf(ch.z, k2.w, a3);
                a0 = fmaf(ch.w, k3.x, a0);
                a1 = fmaf(ch.w, k3.y, a1);
                a2 = fmaf(ch.w, k3.z, a2);
                a3 = fmaf(ch.w, k3.w, a3);
            }
            wcur = wnext;
        }
        float4 r;
        r.x = fmaxf(a0, 0.f);
        r.y = fmaxf(a1, 0.f);
        r.z = fmaxf(a2, 0.f);
        r.w = fmaxf(a3, 0.f);
        return r;
    };

    float4 oL1 = run_layer(W1v, ((const float4*)b1)[jg], wA0, wA1);
    float4 wB0 = W2v[gWb], wB1 = W2v[gWb + 512];
    __syncthreads();                     // h(L0) reads done
    *(float4*)(hrow + j0) = oL1;
    __syncthreads();                     // h(L1) visible
    float4 oL2 = run_layer(W2v, ((const float4*)b2)[jg], wB0, wB1);

    {
        const float4* W3v = (const float4*)W3;
        const float4 wr0 = W3v[jg * 3 + 0];
        const float4 wr1 = W3v[jg * 3 + 1];
        const float4 wr2 = W3v[jg * 3 + 2];
        float p0 = oL2.x * wr0.x + oL2.y * wr0.w + oL2.z * wr1.z + oL2.w * wr2.y;
        float p1 = oL2.x * wr0.y + oL2.y * wr1.x + oL2.z * wr1.w + oL2.w * wr2.z;
        float p2 = oL2.x * wr0.z + oL2.y * wr1.y + oL2.z * wr2.x + oL2.w * wr2.w;
        p0 += __shfl_xor(p0, 16, 64);
        p0 += __shfl_xor(p0, 32, 64);
        p1 += __shfl_xor(p1, 16, 64);
        p1 += __shfl_xor(p1, 32, 64);
        p2 += __shfl_xor(p2, 16, 64);
        p2 += __shfl_xor(p2, 32, 64);
        if (lane < 16) {
            smem[RED + wv * 48 + lane * 3 + 0] = p0;
            smem[RED + wv * 48 + lane * 3 + 1] = p1;
            smem[RED + wv * 48 + lane * 3 + 2] = p2;
        }
    }
    __syncthreads();
    if (tid < 48) {
        const int r = tid / 3, cix = tid - r * 3;
        float v = b3[cix];
#pragma unroll
        for (int g = 0; g < 8; ++g) v += smem[RED + g * 48 + r * 3 + cix];
        smem[SIGL + r * 3 + cix] = __expf(v) * LOG2E;
    }
    __syncthreads();                     // sigl ready; phase-1 arenas dead

    // ========== phase 2: attention, global->reg, ZERO loop LDS ==========
    const int tq = wv & 3;               // target quad
    const int nh = wv >> 2;              // context half (512 n)
    const int ns2 = lane & 15;           // context slot within tile
    const int dg = (lane >> 4) & 1;      // d-half
    const int th = lane >> 5;            // target pair within quad
    const int tb = tq * 4 + th * 2;      // first of this lane's 2 targets
    const int nst = nh * 512;

    const float s00 = smem[SIGL + tb * 3 + 0];
    const float s01 = smem[SIGL + tb * 3 + 1];
    const float s02 = smem[SIGL + tb * 3 + 2];
    const float s10 = smem[SIGL + tb * 3 + 3];
    const float s11 = smem[SIGL + tb * 3 + 4];
    const float s12 = smem[SIGL + tb * 3 + 5];
    const float* arow = xt + (size_t)(t0 + tb) * 3;
    const float a00 = arow[0], a01 = arow[1], a02 = arow[2];
    const float a10 = arow[3], a11 = arow[4], a12 = arow[5];

    const float* __restrict__ xcB = xc + (size_t)b * NCC * 3;
    const float4* __restrict__ ycB4 = (const float4*)(yc + (size_t)b * NCC * DYY);

    float acc0[16], acc1[16];
#pragma unroll
    for (int i = 0; i < 16; ++i) { acc0[i] = 0.f; acc1[i] = 0.f; }
    float l0 = 0.f, l1 = 0.f;

    float4 yA0, yA1, yA2, yA3, yB0, yB1, yB2, yB3;
    float xA0, xA1, xA2, xB0, xB1, xB2;
    PLOAD(0, yA0, yA1, yA2, yA3, xA0, xA1, xA2);
    PLOAD(1, yB0, yB1, yB2, yB3, xB0, xB1, xB2);

    for (int T = 0; T < 32; T += 2) {
        PTILE(xA0, xA1, xA2, yA0, yA1, yA2, yA3);
        if (T < 30) PLOAD(T + 2, yA0, yA1, yA2, yA3, xA0, xA1, xA2);
        PTILE(xB0, xB1, xB2, yB0, yB1, yB2, yB3);
        if (T < 29) PLOAD(T + 3, yB0, yB1, yB2, yB3, xB0, xB1, xB2);
    }

    // ---- dump partials: row = t*32 + nh*16 + ns, width 36 (32 d + l) ----
    {
        const int r0 = tb * 32 + nh * 16 + ns2;
        float* c0 = smem + CMB + r0 * 36 + dg * 16;
        ((float4*)c0)[0] = make_float4(acc0[0], acc0[1], acc0[2], acc0[3]);
        ((float4*)c0)[1] = make_float4(acc0[4], acc0[5], acc0[6], acc0[7]);
        ((float4*)c0)[2] = make_float4(acc0[8], acc0[9], acc0[10], acc0[11]);
        ((float4*)c0)[3] = make_float4(acc0[12], acc0[13], acc0[14], acc0[15]);
        if (dg) smem[CMB + r0 * 36 + 32] = l0;
        const int r1 = r0 + 32;          // target tb+1
        float* c1 = smem + CMB + r1 * 36 + dg * 16;
        ((float4*)c1)[0] = make_float4(acc1[0], acc1[1], acc1[2], acc1[3]);
        ((float4*)c1)[1] = make_float4(acc1[4], acc1[5], acc1[6], acc1[7]);
        ((float4*)c1)[2] = make_float4(acc1[8], acc1[9], acc1[10], acc1[11]);
        ((float4*)c1)[3] = make_float4(acc1[12], acc1[13], acc1[14], acc1[15]);
        if (dg) smem[CMB + r1 * 36 + 32] = l1;
    }
    __syncthreads();

    // ---- combine: each thread owns one (t,d) output ----
    {
        const int t = tid >> 5, d = tid & 31;
        float s = 0.f, ls = 0.f;
#pragma unroll
        for (int q = 0; q < 32; ++q) {   // q = nh*16 + ns
            const int row = t * 32 + q;
            s += smem[CMB + row * 36 + d];
            ls += smem[CMB + row * 36 + 32];
        }
        out[(size_t)(t0 + t) * DYY + d] = s / ls;
    }
}

extern "C" void kernel_launch(void* const* d_in, const int* in_sizes, int n_in,
                              void* d_out, int out_size, void* d_ws, size_t ws_size,
                              hipStream_t stream) {
    const float* xc = (const float*)d_in[0];
    const float* yc = (const float*)d_in[1];
    const float* xt = (const float*)d_in[2];
    const float* W0 = (const float*)d_in[3];
    const float* b0 = (const float*)d_in[4];
    const float* W1 = (const float*)d_in[5];
    const float* b1 = (const float*)d_in[6];
    const float* W2 = (const float*)d_in[7];
    const float* b2 = (const float*)d_in[8];
    const float* W3 = (const float*)d_in[9];
    const float* b3 = (const float*)d_in[10];
    float* out = (float*)d_out;

    k_fused<<<dim3(BB * NTT / NTB), dim3(512), 0, stream>>>(xc, yc, xt, W0, b0,
                                                            W1, b1, W2, b2, W3,
                                                            b3, out);
}

// Round 7
// 128.685 us; speedup vs baseline: 1.1708x; 1.1708x over previous
//
#include <hip/hip_runtime.h>
#include <math.h>

#define BB 8
#define NCC 1024
#define NTT 1024
#define HH 128
#define DYY 32
#define NTB 16                   // 512 blocks x 512 threads
#define LOG2E 1.44269504088896340736f

// LDS arena: 6640 floats = 26.6 KB. Occupancy model (validated r1/r4/r6 +
// prior session): <=~32 KB/block -> 2 blocks/CU; >=42 KB -> 1 block/CU.
// R4/R6 ran at 1 block/CU; this round restores 2.
//   phase 1: HB[0,2112) RED[2112,2496) WCH[2496,6592) SIGL[6592,6640)
//   epilogue: CMB[0,4096) LCMB[4096,4224) alias HB/RED/WCH (dead after the
//   sigl barrier, which all waves pass before any phase-2 work); SIGL disjoint.
#define HB 0
#define RED 2112
#define WCH 2496
#define SIGL 6592
#define SMEM_SZ 6640
#define CMB 0
#define LCMB 4096
#define HSTRIDE 132

// DS-minimization design (r7). Evidence: R0/R1/R4 all plateau 42-47us with
// 10-16k DS wave-instrs/CU ~= the runtime at ~6-12cy/instr; VALUBusy ~33%.
// Phase 2 rebuilt: lane=(ns 0..3, dq 0..3, tq 0..3) owns 4 targets x 8 d;
// y read global->reg (2 dwordx4/step) + xc (3 floats/step), distance-2
// prefetch, 32 steps; e in-lane (dq-redundant: VALU is the idle pipe);
// ns-reduce via DPP quad_perm (VALU, not DS). Phase-2 DS: 256 -> ~25/wave.
// Phase 1 unchanged from r4 (isolate the variable).
// P<=0 (sig>0) => exp(P)<=1: no max subtraction.

__device__ __forceinline__ float quad_add(float v) {
    // butterfly sum over lane bits 0-1 (quad_perm), pure VALU pipe
    int t = __builtin_amdgcn_update_dpp(0, __float_as_int(v), 0xB1, 0xF, 0xF, true);
    v += __int_as_float(t);
    t = __builtin_amdgcn_update_dpp(0, __float_as_int(v), 0x4E, 0xF, 0xF, true);
    v += __int_as_float(t);
    return v;
}

#define P2LOAD(S, Y0, Y1, X0, X1, X2)                                          \
    do {                                                                       \
        const int r_ = rb + (((S) >> 2) << 4) + (((S) & 3) << 2);              \
        const float4* yp_ = ycB4 + r_ * 8 + dq * 2;                            \
        Y0 = yp_[0];                                                           \
        Y1 = yp_[1];                                                           \
        const float* xp_ = xcB + r_ * 3;                                       \
        X0 = xp_[0];                                                           \
        X1 = xp_[1];                                                           \
        X2 = xp_[2];                                                           \
    } while (0)

#define P2STEP(Y0, Y1, X0, X1, X2)                                             \
    do {                                                                       \
        float e_[4];                                                           \
        _Pragma("unroll") for (int tt = 0; tt < 4; ++tt) {                     \
            float d0 = (X0)-at0[tt], d1 = (X1)-at1[tt], d2 = (X2)-at2[tt];     \
            float pp = fmaf(sg0[tt], d0 * d0,                                  \
                            fmaf(sg1[tt], d1 * d1, sg2[tt] * (d2 * d2)));      \
            e_[tt] = exp2f(-pp);                                               \
            lt[tt] += e_[tt];                                                  \
        }                                                                      \
        _Pragma("unroll") for (int tt = 0; tt < 4; ++tt) {                     \
            acc[tt][0] = fmaf(e_[tt], (Y0).x, acc[tt][0]);                     \
            acc[tt][1] = fmaf(e_[tt], (Y0).y, acc[tt][1]);                     \
            acc[tt][2] = fmaf(e_[tt], (Y0).z, acc[tt][2]);                     \
            acc[tt][3] = fmaf(e_[tt], (Y0).w, acc[tt][3]);                     \
            acc[tt][4] = fmaf(e_[tt], (Y1).x, acc[tt][4]);                     \
            acc[tt][5] = fmaf(e_[tt], (Y1).y, acc[tt][5]);                     \
            acc[tt][6] = fmaf(e_[tt], (Y1).z, acc[tt][6]);                     \
            acc[tt][7] = fmaf(e_[tt], (Y1).w, acc[tt][7]);                     \
        }                                                                      \
    } while (0)

__global__ __launch_bounds__(512, 2) void k_fused(const float* __restrict__ xc,
                                                  const float* __restrict__ yc,
                                                  const float* __restrict__ xt,
                                                  const float* __restrict__ W0,
                                                  const float* __restrict__ b0,
                                                  const float* __restrict__ W1,
                                                  const float* __restrict__ b1,
                                                  const float* __restrict__ W2,
                                                  const float* __restrict__ b2,
                                                  const float* __restrict__ W3,
                                                  const float* __restrict__ b3,
                                                  float* __restrict__ out) {
    const int tid = threadIdx.x;
    const int phys = blockIdx.x;
    const int bid = (phys & 7) * 64 + (phys >> 3);   // XCD swizzle (r6: FETCH 1.2MB)
    const int t0 = bid * NTB;
    const int b = bid >> 6;              // 64 blocks per batch
    const int wv = tid >> 6;             // wave 0..7
    const int lane = tid & 63;

    __shared__ float smem[SMEM_SZ];

    // ================= phase 1: MLP (r4 structure, proven) =================
    const int jg = tid >> 4;
    const int p = tid & 15;
    const int j0 = jg * 4;
    const int jl4 = (jg & 3) * 4;
    float* hrow = smem + HB + p * HSTRIDE;

    {
        const float* xr = xt + (size_t)(t0 + p) * 3;
        const float x0 = xr[0], x1 = xr[1], x2 = xr[2];
        const float4* W0v = (const float4*)W0;
        const float4 w0a = W0v[jg], w0b = W0v[32 + jg], w0c = W0v[64 + jg];
        const float4 bb0 = ((const float4*)b0)[jg];
        float4 h0;
        h0.x = fmaxf(fmaf(x0, w0a.x, fmaf(x1, w0b.x, fmaf(x2, w0c.x, bb0.x))), 0.f);
        h0.y = fmaxf(fmaf(x0, w0a.y, fmaf(x1, w0b.y, fmaf(x2, w0c.y, bb0.y))), 0.f);
        h0.z = fmaxf(fmaf(x0, w0a.z, fmaf(x1, w0b.z, fmaf(x2, w0c.z, bb0.z))), 0.f);
        h0.w = fmaxf(fmaf(x0, w0a.w, fmaf(x1, w0b.w, fmaf(x2, w0c.w, bb0.w))), 0.f);
        *(float4*)(hrow + j0) = h0;
    }

    const int gWb = (lane >> 2) * 32 + wv * 4 + (lane & 3);
    float* wwb = smem + WCH + wv * 512;
    const float4* __restrict__ W1v = (const float4*)W1;
    const float4* __restrict__ W2v = (const float4*)W2;

    float4 wA0 = W1v[gWb], wA1 = W1v[gWb + 512];
    __syncthreads();                     // h(L0) visible

    auto run_layer = [&](const float4* __restrict__ Wv, const float4 bi,
                         float4 r0, float4 r1) -> float4 {
        float a0 = bi.x, a1 = bi.y, a2 = bi.z, a3 = bi.w;
        ((float4*)wwb)[lane] = r0;
        float4 wcur = r1;
#pragma unroll
        for (int c = 0; c < 8; ++c) {
            float4 wnext;
            if (c < 6) wnext = Wv[gWb + (c + 2) * 512];
            if (c < 7) ((float4*)(wwb + ((c + 1) & 1) * 256))[lane] = wcur;
            const float* wbc = wwb + (c & 1) * 256;
#pragma unroll
            for (int q = 0; q < 4; ++q) {
                const float4 ch = *(const float4*)(hrow + c * 16 + q * 4);
                const float4 k0 = *(const float4*)(wbc + (q * 4 + 0) * 16 + jl4);
                const float4 k1 = *(const float4*)(wbc + (q * 4 + 1) * 16 + jl4);
                const float4 k2 = *(const float4*)(wbc + (q * 4 + 2) * 16 + jl4);
                const float4 k3 = *(const float4*)(wbc + (q * 4 + 3) * 16 + jl4);
                a0 = fmaf(ch.x, k0.x, a0);
                a1 = fmaf(ch.x, k0.y, a1);
                a2 = fmaf(ch.x, k0.z, a2);
                a3 = fmaf(ch.x, k0.w, a3);
                a0 = fmaf(ch.y, k1.x, a0);
                a1 = fmaf(ch.y, k1.y, a1);
                a2 = fmaf(ch.y, k1.z, a2);
                a3 = fmaf(ch.y, k1.w, a3);
                a0 = fmaf(ch.z, k2.x, a0);
                a1 = fmaf(ch.z, k2.y, a1);
                a2 = fmaf(ch.z, k2.z, a2);
                a3 = fmaf(ch.z, k2.w, a3);
                a0 = fmaf(ch.w, k3.x, a0);
                a1 = fmaf(ch.w, k3.y, a1);
                a2 = fmaf(ch.w, k3.z, a2);
                a3 = fmaf(ch.w, k3.w, a3);
            }
            wcur = wnext;
        }
        float4 r;
        r.x = fmaxf(a0, 0.f);
        r.y = fmaxf(a1, 0.f);
        r.z = fmaxf(a2, 0.f);
        r.w = fmaxf(a3, 0.f);
        return r;
    };

    float4 oL1 = run_layer(W1v, ((const float4*)b1)[jg], wA0, wA1);
    float4 wB0 = W2v[gWb], wB1 = W2v[gWb + 512];
    __syncthreads();                     // h(L0) reads done
    *(float4*)(hrow + j0) = oL1;
    __syncthreads();                     // h(L1) visible
    float4 oL2 = run_layer(W2v, ((const float4*)b2)[jg], wB0, wB1);

    {
        const float4* W3v = (const float4*)W3;
        const float4 wr0 = W3v[jg * 3 + 0];
        const float4 wr1 = W3v[jg * 3 + 1];
        const float4 wr2 = W3v[jg * 3 + 2];
        float p0 = oL2.x * wr0.x + oL2.y * wr0.w + oL2.z * wr1.z + oL2.w * wr2.y;
        float p1 = oL2.x * wr0.y + oL2.y * wr1.x + oL2.z * wr1.w + oL2.w * wr2.z;
        float p2 = oL2.x * wr0.z + oL2.y * wr1.y + oL2.z * wr2.x + oL2.w * wr2.w;
        p0 += __shfl_xor(p0, 16, 64);
        p0 += __shfl_xor(p0, 32, 64);
        p1 += __shfl_xor(p1, 16, 64);
        p1 += __shfl_xor(p1, 32, 64);
        p2 += __shfl_xor(p2, 16, 64);
        p2 += __shfl_xor(p2, 32, 64);
        if (lane < 16) {
            smem[RED + wv * 48 + lane * 3 + 0] = p0;
            smem[RED + wv * 48 + lane * 3 + 1] = p1;
            smem[RED + wv * 48 + lane * 3 + 2] = p2;
        }
    }
    __syncthreads();
    if (tid < 48) {
        const int r = tid / 3, cix = tid - r * 3;
        float v = b3[cix];
#pragma unroll
        for (int g = 0; g < 8; ++g) v += smem[RED + g * 48 + r * 3 + cix];
        smem[SIGL + r * 3 + cix] = __expf(v) * LOG2E;
    }
    __syncthreads();                     // sigl ready; phase-1 arenas dead

    // ========== phase 2: global->reg y, in-lane e, DPP reduce ==========
    const int ns = lane & 3;             // row slot (DPP quad axis)
    const int dq = (lane >> 2) & 3;      // d-quarter (8 floats)
    const int tq = lane >> 4;            // target quad
    const int tb = tq * 4;

    float sg0[4], sg1[4], sg2[4], at0[4], at1[4], at2[4];
    {
        const float4* sv = (const float4*)(smem + SIGL + tb * 3);
        const float4 s_a = sv[0], s_b = sv[1], s_c = sv[2];
        sg0[0] = s_a.x; sg1[0] = s_a.y; sg2[0] = s_a.z;
        sg0[1] = s_a.w; sg1[1] = s_b.x; sg2[1] = s_b.y;
        sg0[2] = s_b.z; sg1[2] = s_b.w; sg2[2] = s_c.x;
        sg0[3] = s_c.y; sg1[3] = s_c.z; sg2[3] = s_c.w;
        const float4* av = (const float4*)(xt + (size_t)(t0 + tb) * 3);
        const float4 a_a = av[0], a_b = av[1], a_c = av[2];
        at0[0] = a_a.x; at1[0] = a_a.y; at2[0] = a_a.z;
        at0[1] = a_a.w; at1[1] = a_b.x; at2[1] = a_b.y;
        at0[2] = a_b.z; at1[2] = a_b.w; at2[2] = a_c.x;
        at0[3] = a_c.y; at1[3] = a_c.z; at2[3] = a_c.w;
    }

    const float* __restrict__ xcB = xc + (size_t)b * NCC * 3;
    const float4* __restrict__ ycB4 = (const float4*)(yc + (size_t)b * NCC * DYY);
    const int rb = wv * 128 + ns;        // lane row = rb + (s>>2)*16 + (s&3)*4

    float acc[4][8];
    float lt[4];
#pragma unroll
    for (int tt = 0; tt < 4; ++tt) {
        lt[tt] = 0.f;
#pragma unroll
        for (int k = 0; k < 8; ++k) acc[tt][k] = 0.f;
    }

    float4 yA0, yA1, yB0, yB1;
    float xA0, xA1, xA2, xB0, xB1, xB2;
    P2LOAD(0, yA0, yA1, xA0, xA1, xA2);
    P2LOAD(1, yB0, yB1, xB0, xB1, xB2);

#pragma unroll 4
    for (int s = 0; s < 32; s += 2) {
        P2STEP(yA0, yA1, xA0, xA1, xA2);
        if (s < 30) P2LOAD(s + 2, yA0, yA1, xA0, xA1, xA2);
        P2STEP(yB0, yB1, xB0, xB1, xB2);
        if (s < 29) P2LOAD(s + 3, yB0, yB1, xB0, xB1, xB2);
    }

    // ---- ns-reduce on VALU (DPP), dump 4KB CMB, combine ----
#pragma unroll
    for (int tt = 0; tt < 4; ++tt) {
#pragma unroll
        for (int k = 0; k < 8; ++k) acc[tt][k] = quad_add(acc[tt][k]);
        lt[tt] = quad_add(lt[tt]);
    }
    if (ns == 0) {
#pragma unroll
        for (int tt = 0; tt < 4; ++tt) {
            const int t = tb + tt;
            float* cp = smem + CMB + t * 256 + wv * 32 + dq * 8;
            *(float4*)cp = make_float4(acc[tt][0], acc[tt][1], acc[tt][2], acc[tt][3]);
            *(float4*)(cp + 4) = make_float4(acc[tt][4], acc[tt][5], acc[tt][6], acc[tt][7]);
            if (dq == 0) smem[LCMB + t * 8 + wv] = lt[tt];
        }
    }
    __syncthreads();
    {
        const int t = tid >> 5, d = tid & 31;   // each thread owns one output
        float s = 0.f, ls = 0.f;
#pragma unroll
        for (int w = 0; w < 8; ++w) {
            s += smem[CMB + t * 256 + w * 32 + d];
            ls += smem[LCMB + t * 8 + w];
        }
        out[(size_t)(t0 + t) * DYY + d] = s / ls;
    }
}

extern "C" void kernel_launch(void* const* d_in, const int* in_sizes, int n_in,
                              void* d_out, int out_size, void* d_ws, size_t ws_size,
                              hipStream_t stream) {
    const float* xc = (const float*)d_in[0];
    const float* yc = (const float*)d_in[1];
    const float* xt = (const float*)d_in[2];
    const float* W0 = (const float*)d_in[3];
    const float* b0 = (const float*)d_in[4];
    const float* W1 = (const float*)d_in[5];
    const float* b1 = (const float*)d_in[6];
    const float* W2 = (const float*)d_in[7];
    const float* b2 = (const float*)d_in[8];
    const float* W3 = (const float*)d_in[9];
    const float* b3 = (const float*)d_in[10];
    float* out = (float*)d_out;

    k_fused<<<dim3(BB * NTT / NTB), dim3(512), 0, stream>>>(xc, yc, xt, W0, b0,
                                                            W1, b1, W2, b2, W3,
                                                            b3, out);
}